// Round 1
// baseline (245.217 us; speedup 1.0000x reference)
//
#include <hip/hip_runtime.h>

#define S_DIM 2048
#define K_DIM 4096
#define O_DIM 4096
#define NNON  3968   // H - KEEPER
#define NB    31     // low-precision blocks

#define XBLK 8192    // scale_x segment blocks:  S*K/4/256
#define WBLK 16384   // scale_w segment blocks:  O*K/4/256

typedef __bf16 bf16x8 __attribute__((ext_vector_type(8)));
typedef float  f32x4  __attribute__((ext_vector_type(4)));

__device__ __forceinline__ unsigned short f2bf(float f) {
    union { float f; unsigned u; } v; v.f = f;
    unsigned r = v.u + 0x7FFFu + ((v.u >> 16) & 1u);   // round-to-nearest-even
    return (unsigned short)(r >> 16);
}

// One fused prepass launch, two block-uniform segments:
//   [0, XBLK)           A'[s,k] = bf16(x * sc_lo/hi)
//   [XBLK, XBLK+WBLK)   B'[o,k] = bf16(w * scales/keep)
__global__ __launch_bounds__(256) void prepass(const float* __restrict__ x,
                                               const float* __restrict__ sc_lo,
                                               const float* __restrict__ sc_hi,
                                               const float* __restrict__ w,
                                               const float* __restrict__ scales,
                                               const float* __restrict__ keep,
                                               unsigned short* __restrict__ A,
                                               unsigned short* __restrict__ B)
{
    const int b = blockIdx.x;
    if (b < XBLK) {
        int idx = b * 256 + threadIdx.x;           // over S*K/4, K/4 = 1024
        int s = idx >> 10;
        int k = (idx & 1023) << 2;                 // 4 elems never straddle a 128-block
        float4 v = ((const float4*)x)[idx];
        float sc = (k < NNON) ? sc_lo[s * NB + (k >> 7)] : sc_hi[s];
        ushort4 o;
        o.x = f2bf(v.x * sc); o.y = f2bf(v.y * sc);
        o.z = f2bf(v.z * sc); o.w = f2bf(v.w * sc);
        ((ushort4*)A)[idx] = o;
    } else {
        int idx = (b - XBLK) * 256 + threadIdx.x;  // over O*K/4
        int o = idx >> 10;
        int k = (idx & 1023) << 2;
        float4 v = ((const float4*)w)[idx];
        float sc = (k < NNON) ? scales[(size_t)o * NNON + ((k >> 7) << 7)] : keep[o];
        ushort4 r;
        r.x = f2bf(v.x * sc); r.y = f2bf(v.y * sc);
        r.z = f2bf(v.z * sc); r.w = f2bf(v.w * sc);
        ((ushort4*)B)[idx] = r;
    }
}

// R7: port GEMM to the 8-wave counted-vmcnt phase schedule (T1+T3+T4+T5,
// m201-style) at BM=128 x BN=256, BK=64 (256 WGs -- a 256^2 tile would give
// only 128 WGs at M=2048 and idle half the chip).
//   - 512 threads = 8 waves (2M x 4N), 64x64 output per wave.
//   - LDS 96 KB: double-buffered As[128x64] + Bs[256x64], XOR chunk swizzle
//     (8 x 16B chunks/row, slot = chunk ^ (row&7)) applied on the global
//     source column (global_load_lds dest must stay linear), un-swizzled on
//     ds_read. Worst-case 2-way bank aliasing (free per m136).
//   - Per K-tile, 2 phases: {12 ds_read; s_barrier; stage A(t+2) [2 DMA];
//     setprio(1); 16 MFMA} then {4 ds_read; s_barrier; stage B(t+2) [4 DMA];
//     setprio(1); 16 MFMA; s_waitcnt vmcnt(6); s_barrier}.
//     vmcnt(6) (never 0 in the main loop) leaves tile t+2's 6 loads in
//     flight across the barrier; tile t+1 is guaranteed resident because
//     the barrier comes AFTER every wave's counted wait.
//   - Phase-safety: phase 1 reads ALL of A and B[0:32] before its barrier,
//     so staging A(t+2) into the same buffer is race-free; all B reads are
//     issued before the phase-2 barrier, so staging B(t+2) is race-free.
#define BM 128
#define BN 256
#define BK 64
#define NT (K_DIM / BK)   // 64 K-tiles

#define GPTR(p) ((__attribute__((address_space(1))) unsigned int*)(p))
#define LPTR(p) ((__attribute__((address_space(3))) unsigned int*)(p))

__device__ __forceinline__ void vm_wait6() { asm volatile("s_waitcnt vmcnt(6)" ::: "memory"); }
__device__ __forceinline__ void vm_wait0() { asm volatile("s_waitcnt vmcnt(0)" ::: "memory"); }
__device__ __forceinline__ void wg_barrier() {
    asm volatile("" ::: "memory");
    __builtin_amdgcn_s_barrier();
    asm volatile("" ::: "memory");
}

__global__ __launch_bounds__(512, 2) void gemm_bt(const unsigned short* __restrict__ A,
                                                  const unsigned short* __restrict__ B,
                                                  float* __restrict__ C)
{
    __shared__ __align__(16) unsigned short As[2][BM * BK];   // 2 x 16 KB
    __shared__ __align__(16) unsigned short Bs[2][BN * BK];   // 2 x 32 KB

    const int tid  = threadIdx.x;
    const int wave = tid >> 6;        // 0..7
    const int lane = tid & 63;
    const int quad = lane >> 4;
    const int l16  = lane & 15;

    // XCD-aware bijective swizzle: 256 WGs, 8 XCDs, 32 contiguous tiles/XCD.
    const int wg = blockIdx.x;                   // 0..255
    const int sw = (wg & 7) * 32 + (wg >> 3);
    const int bm = (sw >> 4) * BM;               // 16 M-tiles
    const int bn = (sw & 15) * BN;               // 16 N-tiles

    const int wm = (wave >> 2) * 64;             // wave row offset in tile
    const int wn = (wave & 3) * 64;              // wave col offset in tile

    // staging: each DMA slot = 64 rows (8 waves x 8 rows), lane covers
    // row r8 = lane>>3, dest 16B chunk q8 = lane&7; source column chunk
    // pre-swizzled: q8 ^ (row&7) = q8 ^ r8 (slot/wave bases are %8 == 0).
    const int r8 = lane >> 3;
    const int q8 = lane & 7;
    const unsigned short* Ag = A + (size_t)(bm + wave * 8 + r8) * K_DIM + ((q8 ^ r8) << 3);
    const unsigned short* Bg = B + (size_t)(bn + wave * 8 + r8) * K_DIM + ((q8 ^ r8) << 3);

    f32x4 acc[4][4];
    #pragma unroll
    for (int i = 0; i < 4; ++i)
        #pragma unroll
        for (int j = 0; j < 4; ++j)
            acc[i][j] = (f32x4){0.f, 0.f, 0.f, 0.f};

    auto stageA = [&](int t) {   // 2 global_load_lds / thread
        unsigned short* dst = &As[t & 1][wave * 8 * BK];
        #pragma unroll
        for (int s = 0; s < 2; ++s)
            __builtin_amdgcn_global_load_lds(GPTR(Ag + (size_t)(s * 64) * K_DIM + t * BK),
                                             LPTR(dst + s * 64 * BK), 16, 0, 0);
    };
    auto stageB = [&](int t) {   // 4 global_load_lds / thread
        unsigned short* dst = &Bs[t & 1][wave * 8 * BK];
        #pragma unroll
        for (int s = 0; s < 4; ++s)
            __builtin_amdgcn_global_load_lds(GPTR(Bg + (size_t)(s * 64) * K_DIM + t * BK),
                                             LPTR(dst + s * 64 * BK), 16, 0, 0);
    };

    // prologue: tiles 0 and 1 in flight (12 loads); wait tile 0 (leave 6)
    stageA(0); stageB(0);
    stageA(1); stageB(1);
    vm_wait6();
    wg_barrier();

    #pragma unroll 2
    for (int t = 0; t < NT; ++t) {
        const int cur = t & 1;
        const unsigned short* asb = As[cur];
        const unsigned short* bsb = Bs[cur];

        // ---------------- phase 1: all A frags + B cols 0..31 ----------------
        bf16x8 af[2][4], b01[2][2];
        #pragma unroll
        for (int ks = 0; ks < 2; ++ks) {
            #pragma unroll
            for (int i = 0; i < 4; ++i)
                af[ks][i] = *(const bf16x8*)&asb[(wm + i * 16 + l16) * BK +
                                                 (((ks * 4 + quad) ^ (l16 & 7)) << 3)];
            #pragma unroll
            for (int j = 0; j < 2; ++j)
                b01[ks][j] = *(const bf16x8*)&bsb[(wn + j * 16 + l16) * BK +
                                                  (((ks * 4 + quad) ^ (l16 & 7)) << 3)];
        }
        wg_barrier();                       // all waves done reading As + B[0:32]
        if (t < NT - 2) stageA(t + 2);      // overwrite As[cur]: safe

        __builtin_amdgcn_s_setprio(1);
        #pragma unroll
        for (int ks = 0; ks < 2; ++ks)
            #pragma unroll
            for (int i = 0; i < 4; ++i)
                #pragma unroll
                for (int j = 0; j < 2; ++j)
                    acc[i][j] = __builtin_amdgcn_mfma_f32_16x16x32_bf16(af[ks][i], b01[ks][j],
                                                                        acc[i][j], 0, 0, 0);
        __builtin_amdgcn_s_setprio(0);

        // ---------------- phase 2: B cols 32..63 ----------------
        bf16x8 b23[2][2];
        #pragma unroll
        for (int ks = 0; ks < 2; ++ks)
            #pragma unroll
            for (int j = 0; j < 2; ++j)
                b23[ks][j] = *(const bf16x8*)&bsb[(wn + (j + 2) * 16 + l16) * BK +
                                                  (((ks * 4 + quad) ^ (l16 & 7)) << 3)];
        wg_barrier();                       // all waves done reading Bs[cur]
        if (t < NT - 2) stageB(t + 2);      // overwrite Bs[cur]: safe

        __builtin_amdgcn_s_setprio(1);
        #pragma unroll
        for (int ks = 0; ks < 2; ++ks)
            #pragma unroll
            for (int i = 0; i < 4; ++i)
                #pragma unroll
                for (int j = 0; j < 2; ++j)
                    acc[i][j + 2] = __builtin_amdgcn_mfma_f32_16x16x32_bf16(af[ks][i], b23[ks][j],
                                                                            acc[i][j + 2], 0, 0, 0);
        __builtin_amdgcn_s_setprio(0);

        // counted wait: tile t+1 resident, tile t+2's 6 loads stay in flight.
        if (t < NT - 2)       vm_wait6();
        else if (t == NT - 2) vm_wait0();   // drain last prefetch (tile NT-1)
        wg_barrier();                       // after-vmcnt barrier covers all waves' loads
    }

    // C/D layout (m89-verified): col = lane&15, row = quad*4 + reg
    #pragma unroll
    for (int i = 0; i < 4; ++i)
        #pragma unroll
        for (int j = 0; j < 4; ++j) {
            const int col = bn + wn + j * 16 + l16;
            #pragma unroll
            for (int r = 0; r < 4; ++r) {
                const int row = bm + wm + i * 16 + quad * 4 + r;
                C[(size_t)row * O_DIM + col] = acc[i][j][r];
            }
        }
}

extern "C" void kernel_launch(void* const* d_in, const int* in_sizes, int n_in,
                              void* d_out, int out_size, void* d_ws, size_t ws_size,
                              hipStream_t stream) {
    const float* x      = (const float*)d_in[0];
    const float* weight = (const float*)d_in[1];  // [O, K]
    const float* scales = (const float*)d_in[2];  // [O, NNON]
    const float* keep   = (const float*)d_in[3];  // [O, 1]
    const float* sc_lo  = (const float*)d_in[4];  // [S, NB]
    const float* sc_hi  = (const float*)d_in[5];  // [S, 1]
    // d_in[6], d_in[7] (inp_base_lo/hi) unused by reference

    // workspace: A' 16 MB @ 0, B' 32 MB @ 16 MB (needs 48 MB of d_ws)
    unsigned short* A = (unsigned short*)d_ws;
    unsigned short* B = A + (size_t)S_DIM * K_DIM;

    prepass<<<XBLK + WBLK, 256, 0, stream>>>(x, sc_lo, sc_hi, weight, scales, keep, A, B);

    dim3 grid(256);   // 16 M-tiles x 16 N-tiles, XCD-swizzled in-kernel
    gemm_bt<<<grid, 512, 0, stream>>>(A, B, (float*)d_out);
}